// Round 4
// baseline (137.645 us; speedup 1.0000x reference)
//
#include <hip/hip_runtime.h>
#include <hip/hip_bf16.h>

// Problem: B=4, N=2048, C=512, H=8, D=64, L=64, SCALE=0.125. Inputs f32, output f32.
// No softmax => attention is linear => reassociate:
//   out[b] = (x[b]@Wq * SCALE)(2048x512) @ Wcat[b](512x64)
//   Wcat[b][h*64+dq][:] = ( sum_m k[b,m,h,dq] * v[m,h,:] ) @ proj_h
// KV accumulated via f32 atomics (512 KB) instead of a 8.4 MB partials round-trip.

using f32x4 = __attribute__((ext_vector_type(4))) float;
using s16x8 = __attribute__((ext_vector_type(8))) short;  // 8 bf16 (4 VGPRs), MFMA operand

__device__ __forceinline__ unsigned short f2bf(float f) {
  unsigned int i;
  __builtin_memcpy(&i, &f, 4);
  unsigned int lsb = (i >> 16) & 1u;
  i += 0x7fffu + lsb;  // round-to-nearest-even
  return (unsigned short)(i >> 16);
}
__device__ __forceinline__ float bf2f(unsigned short u) {
  unsigned int i = ((unsigned int)u) << 16;
  float f;
  __builtin_memcpy(&f, &i, 4);
  return f;
}
__device__ __forceinline__ void async_cp16(const void* g, void* l) {
  // 16B global->LDS DMA; LDS dest must be WAVE-UNIFORM base (HW adds lane*16)
  __builtin_amdgcn_global_load_lds((const __attribute__((address_space(1))) void*)g,
                                   (__attribute__((address_space(3))) void*)l, 16, 0, 0);
}

// ---------------- 1) prep: convert x (0..2047), transpose qkv (2048..2559), zero KV (2560..2591)
__global__ void k_prep(const float* __restrict__ x, const float* __restrict__ qkv,
                       unsigned short* __restrict__ xb, unsigned short* __restrict__ qkvT,
                       float* __restrict__ KV) {
  const int id = blockIdx.x;
  const int tid = threadIdx.x;
  if (id < 2048) {
    size_t i = ((size_t)id * 256 + tid) * 8;
    f32x4 a = *(const f32x4*)(x + i);
    f32x4 b = *(const f32x4*)(x + i + 4);
    ushort4 lo, hi;
    lo.x = f2bf(a[0]); lo.y = f2bf(a[1]); lo.z = f2bf(a[2]); lo.w = f2bf(a[3]);
    hi.x = f2bf(b[0]); hi.y = f2bf(b[1]); hi.z = f2bf(b[2]); hi.w = f2bf(b[3]);
    *(ushort4*)(xb + i) = lo;
    *(ushort4*)(xb + i + 4) = hi;
  } else if (id < 2560) {
    // qkvT[s*512+h*64+d][c] = qkv[c][h*128+s*64+d]
    __shared__ float tile[32][33];
    const int idx = id - 2048;
    const int j0 = (idx & 31) * 32;
    const int c0 = (idx >> 5) * 32;
    const int tx = tid & 31, ty = tid >> 5;  // 32 x 8
#pragma unroll
    for (int i = 0; i < 32; i += 8)
      tile[ty + i][tx] = qkv[(size_t)(c0 + ty + i) * 1024 + j0 + tx];
    __syncthreads();
    const int h = j0 >> 7, s = (j0 >> 6) & 1, d0 = j0 & 63;
    const int jp0 = s * 512 + h * 64 + d0;
#pragma unroll
    for (int i = 0; i < 32; i += 8)
      qkvT[(size_t)(jp0 + ty + i) * 512 + c0 + tx] = f2bf(tile[tx][ty + i]);
  } else {
    // zero KV[bh] (4096 f32 per block)
    float* dst = KV + (size_t)(id - 2560) * 4096;
    f32x4 z = {0.f, 0.f, 0.f, 0.f};
#pragma unroll
    for (int j = 0; j < 4; ++j)
      *(f32x4*)(dst + j * 1024 + tid * 4) = z;
  }
}

// ---------------- 2) GEMM1 (8 waves, double-buffered): xb(8192x512) @ qkvT^T -> Q (scaled), K
__global__ __launch_bounds__(512) void k_gemm1(
    const unsigned short* __restrict__ A,   // xb [8192][512] bf16
    const unsigned short* __restrict__ Bt,  // qkvT [1024][512] bf16
    unsigned short* __restrict__ Qws,       // [8192][512] col = h*64+d
    unsigned short* __restrict__ Kws) {     // [8192][512]
  __shared__ unsigned short As[2][128 * 64];
  __shared__ unsigned short Bs[2][128 * 64];
  const int m0 = blockIdx.x * 128;
  const int n0 = blockIdx.y * 128;
  const int tid = threadIdx.x;
  const int lane = tid & 63;
  const int wave = tid >> 6;       // 8 waves: wm 4 x wn 2
  const int wm = wave >> 1, wn = wave & 1;

  f32x4 acc[2][4] = {};

  const int rlane = lane >> 3;        // row within wave's 8-row stage group
  const int clane = (lane & 7) * 8;   // 8 bf16 = 16B

#define STAGE(buf, kt)                                                              \
  {                                                                                 \
    _Pragma("unroll") for (int i = 0; i < 2; ++i) {                                 \
      async_cp16(A + (size_t)(m0 + i * 64 + wave * 8 + rlane) * 512 + (kt) + clane, \
                 As[buf] + (i * 64 + wave * 8) * 64);                               \
      async_cp16(Bt + (size_t)(n0 + i * 64 + wave * 8 + rlane) * 512 + (kt) + clane,\
                 Bs[buf] + (i * 64 + wave * 8) * 64);                               \
    }                                                                               \
  }

#define COMPUTE(buf)                                                                       \
  {                                                                                        \
    _Pragma("unroll") for (int kk = 0; kk < 64; kk += 32) {                                \
      s16x8 af[2], bfr[4];                                                                 \
      _Pragma("unroll") for (int i = 0; i < 2; ++i)                                        \
        af[i] = *(const s16x8*)(As[buf] + (wm * 32 + i * 16 + (lane & 15)) * 64 + kk +     \
                                (lane >> 4) * 8);                                          \
      _Pragma("unroll") for (int j = 0; j < 4; ++j)                                        \
        bfr[j] = *(const s16x8*)(Bs[buf] + (wn * 64 + j * 16 + (lane & 15)) * 64 + kk +    \
                                 (lane >> 4) * 8);                                         \
      _Pragma("unroll") for (int i = 0; i < 2; ++i)                                        \
        _Pragma("unroll") for (int j = 0; j < 4; ++j)                                      \
          acc[i][j] = __builtin_amdgcn_mfma_f32_16x16x32_bf16(af[i], bfr[j], acc[i][j],    \
                                                              0, 0, 0);                    \
    }                                                                                      \
  }

  STAGE(0, 0);
  __syncthreads();          // drains vmcnt: buf0 ready
  int cur = 0;
  for (int kt = 64; kt < 512; kt += 64) {
    STAGE(cur ^ 1, kt);     // issue next tile's loads (overlap with MFMA below)
    COMPUTE(cur);
    __syncthreads();        // drains vmcnt+lgkmcnt: next buf ready, cur free for re-stage
    cur ^= 1;
  }
  COMPUTE(cur);
#undef STAGE
#undef COMPUTE

  const int n_base = n0 + wn * 64;
#pragma unroll
  for (int i = 0; i < 2; ++i) {
    int grow = m0 + wm * 32 + i * 16 + (lane >> 4) * 4;
#pragma unroll
    for (int j = 0; j < 4; ++j) {
      int gcol = n_base + j * 16 + (lane & 15);
      unsigned short* dst;
      float scale;
      if (gcol < 512) { dst = Qws; scale = 0.125f; }        // q, fold SCALE (exact pow2)
      else            { dst = Kws; gcol -= 512; scale = 1.0f; }
#pragma unroll
      for (int r = 0; r < 4; ++r)
        dst[(size_t)(grow + r) * 512 + gcol] = f2bf(acc[i][j][r] * scale);
    }
  }
}

// ---------------- 3) KV partials: atomicAdd into KV[b][h][dq][l] (f32, 512 KB)
__global__ void k_kv_partial(const unsigned short* __restrict__ Kws,
                             const float* __restrict__ v,   // [2048][512] f32, col h*64+l
                             float* __restrict__ KV) {
  const int wg = blockIdx.x;      // b*128 + h*16 + chunk
  const int chunk = wg & 15;
  const int h = (wg >> 4) & 7;
  const int b = wg >> 7;
  __shared__ unsigned short Ks[128 * 64];  // 16 KB bf16
  __shared__ float Vs[128 * 64];           // 32 KB f32
  const int tid = threadIdx.x;
  const int lane = tid & 63;
  const int wave = tid >> 6;
  const int n0 = chunk * 128;
  // K staging: 8 lanes/row (16B = 8 bf16), 8 rows/call, 4 calls -> 32 rows/wave
  {
    const int r = wave * 32 + (lane >> 3);
    const int c = (lane & 7) * 8;
#pragma unroll
    for (int i = 0; i < 4; ++i)
      async_cp16(Kws + (size_t)(b * 2048 + n0 + r + i * 8) * 512 + h * 64 + c,
                 Ks + (wave * 32 + i * 8) * 64);
  }
  // V staging (f32): 16 lanes/row (16B = 4 f32), 4 rows/call, 8 calls -> 32 rows/wave
  {
    const int r = wave * 32 + (lane >> 4);
    const int c = (lane & 15) * 4;
#pragma unroll
    for (int i = 0; i < 8; ++i)
      async_cp16(v + (size_t)(n0 + r + i * 4) * 512 + h * 64 + c,
                 Vs + (wave * 32 + i * 4) * 64);
  }
  __syncthreads();
  const int dq0 = (tid & 15) * 4;
  const int l0 = (tid >> 4) * 4;
  float acc[4][4] = {};
#pragma unroll 4
  for (int n = 0; n < 128; ++n) {
    ushort4 ku = *(const ushort4*)(Ks + n * 64 + dq0);
    f32x4 va = *(const f32x4*)(Vs + n * 64 + l0);
    float ka[4] = {bf2f(ku.x), bf2f(ku.y), bf2f(ku.z), bf2f(ku.w)};
#pragma unroll
    for (int a = 0; a < 4; ++a)
#pragma unroll
      for (int c = 0; c < 4; ++c)
        acc[a][c] += ka[a] * va[c];
  }
  float* dst = KV + (size_t)(b * 8 + h) * 4096;
#pragma unroll
  for (int a = 0; a < 4; ++a)
#pragma unroll
    for (int c = 0; c < 4; ++c)
      atomicAdd(dst + (dq0 + a) * 64 + l0 + c, acc[a][c]);
}

// ---------------- 4) W = KV@proj_h -> WcatT[b][dout][h*64+dq] (bf16); 32 blocks, tiny reads
__global__ void k_w(const float* __restrict__ KV,
                    const float* __restrict__ proj,   // [512][64] f32
                    unsigned short* __restrict__ WcatT) {  // [B][64][512]
  const int bh = blockIdx.x;  // b*8 + h
  const int h = bh & 7;
  const int b = bh >> 3;
  __shared__ float kv[64 * 65];   // padded: conflict-free column reads
  __shared__ float pj[64 * 64];
  const int tid = threadIdx.x;
#pragma unroll
  for (int j = 0; j < 16; ++j) {
    int e = tid + j * 256;
    kv[(e >> 6) * 65 + (e & 63)] = KV[(size_t)bh * 4096 + e];
  }
#pragma unroll
  for (int j = 0; j < 16; ++j) {
    int e = tid + j * 256;
    pj[e] = proj[(size_t)(h * 64 + (e >> 6)) * 64 + (e & 63)];
  }
  __syncthreads();
  const int dq = tid >> 2;
  const int d0 = (tid & 3) * 16;
  f32x4 w[4] = {};
  for (int l = 0; l < 64; ++l) {
    float kvv = kv[dq * 65 + l];
#pragma unroll
    for (int jj = 0; jj < 4; ++jj) {
      f32x4 p4 = *(const f32x4*)(pj + l * 64 + d0 + jj * 4);
      w[jj] += kvv * p4;
    }
  }
#pragma unroll
  for (int jj = 0; jj < 4; ++jj)
#pragma unroll
    for (int q = 0; q < 4; ++q)
      WcatT[(size_t)(b * 64 + d0 + jj * 4 + q) * 512 + h * 64 + dq] = f2bf(w[jj][q]);
}

// ---------------- 5) GEMM2 streaming: out[b] = Qws[b](2048x512) @ WcatT[b]^T(512x64)
// 512 blocks x 1 wave; 16-row m-tile per wave; no LDS, no barriers. All operands L2-hot.
__global__ __launch_bounds__(64) void k_gemm2(
    const unsigned short* __restrict__ Qws,
    const unsigned short* __restrict__ WcatT,
    float* __restrict__ out) {   // [8192][64] f32
  const int m0 = blockIdx.x * 16;
  const int lane = threadIdx.x;
  const unsigned short* Bb = WcatT + (size_t)(m0 >> 11) * 64 * 512;
  const int arow = lane & 15;
  const int koff = (lane >> 4) * 8;
  f32x4 acc[4] = {};
#pragma unroll
  for (int kk = 0; kk < 16; ++kk) {
    s16x8 af = *(const s16x8*)(Qws + (size_t)(m0 + arow) * 512 + kk * 32 + koff);
#pragma unroll
    for (int j = 0; j < 4; ++j) {
      s16x8 bf = *(const s16x8*)(Bb + (size_t)(j * 16 + arow) * 512 + kk * 32 + koff);
      acc[j] = __builtin_amdgcn_mfma_f32_16x16x32_bf16(af, bf, acc[j], 0, 0, 0);
    }
  }
  const int grow = m0 + (lane >> 4) * 4;
#pragma unroll
  for (int j = 0; j < 4; ++j) {
    int gcol = j * 16 + arow;
#pragma unroll
    for (int r = 0; r < 4; ++r)
      out[(size_t)(grow + r) * 64 + gcol] = acc[j][r];
  }
}

extern "C" void kernel_launch(void* const* d_in, const int* in_sizes, int n_in,
                              void* d_out, int out_size, void* d_ws, size_t ws_size,
                              hipStream_t stream) {
  const float* x    = (const float*)d_in[0];  // [4][2048][512] f32
  const float* v    = (const float*)d_in[1];  // [2048][8][64]  f32
  const float* qkv  = (const float*)d_in[2];  // [512][1024]    f32
  const float* proj = (const float*)d_in[3];  // [512][64]      f32
  float* out = (float*)d_out;                 // [4][2048][64]  f32

  char* ws = (char*)d_ws;
  unsigned short* xb   = (unsigned short*)ws; ws += (size_t)8192 * 512 * 2;  // 8.4 MB
  unsigned short* qkvT = (unsigned short*)ws; ws += (size_t)1024 * 512 * 2;  // 1 MB
  unsigned short* Qws  = (unsigned short*)ws; ws += (size_t)8192 * 512 * 2;  // 8.4 MB
  unsigned short* Kws  = (unsigned short*)ws; ws += (size_t)8192 * 512 * 2;  // 8.4 MB
  float*          KV   = (float*)ws;          ws += (size_t)32 * 4096 * 4;   // 512 KB
  unsigned short* Wc   = (unsigned short*)ws; ws += (size_t)4 * 64 * 512 * 2;

  hipLaunchKernelGGL(k_prep, dim3(2592), dim3(256), 0, stream, x, qkv, xb, qkvT, KV);
  hipLaunchKernelGGL(k_gemm1, dim3(64, 8), dim3(512), 0, stream, xb, qkvT, Qws, Kws);
  hipLaunchKernelGGL(k_kv_partial, dim3(512), dim3(256), 0, stream, Kws, v, KV);
  hipLaunchKernelGGL(k_w, dim3(32), dim3(256), 0, stream, KV, proj, Wc);
  hipLaunchKernelGGL(k_gemm2, dim3(512), dim3(64), 0, stream, Qws, Wc, out);
}

// Round 5
// 112.518 us; speedup vs baseline: 1.2233x; 1.2233x over previous
//
#include <hip/hip_runtime.h>
#include <hip/hip_bf16.h>

// Problem: B=4, N=2048, C=512, H=8, D=64, L=64, SCALE=0.125. Inputs f32, output f32.
// No softmax => attention is linear => reassociate:
//   out[b] = (x[b]@Wq * SCALE)(2048x512) @ Wcat[b](512x64)
//   Wcat[b][h*64+dq][:] = ( sum_m k[b,m,h,dq] * v[m,h,:] ) @ proj_h

using f32x4 = __attribute__((ext_vector_type(4))) float;
using s16x8 = __attribute__((ext_vector_type(8))) short;  // 8 bf16 (4 VGPRs), MFMA operand

__device__ __forceinline__ unsigned short f2bf(float f) {
  unsigned int i;
  __builtin_memcpy(&i, &f, 4);
  unsigned int lsb = (i >> 16) & 1u;
  i += 0x7fffu + lsb;  // round-to-nearest-even
  return (unsigned short)(i >> 16);
}
__device__ __forceinline__ float bf2f(unsigned short u) {
  unsigned int i = ((unsigned int)u) << 16;
  float f;
  __builtin_memcpy(&f, &i, 4);
  return f;
}
__device__ __forceinline__ void async_cp16(const void* g, void* l) {
  // 16B global->LDS DMA; LDS dest must be WAVE-UNIFORM base (HW adds lane*16)
  __builtin_amdgcn_global_load_lds((const __attribute__((address_space(1))) void*)g,
                                   (__attribute__((address_space(3))) void*)l, 16, 0, 0);
}

// ---------------- 1) prep: convert x f32->bf16 (blocks 0..2047), transpose qkv (2048..2559)
__global__ void k_prep(const float* __restrict__ x, const float* __restrict__ qkv,
                       unsigned short* __restrict__ xb, unsigned short* __restrict__ qkvT) {
  const int id = blockIdx.x;
  const int tid = threadIdx.x;
  if (id < 2048) {
    size_t i = ((size_t)id * 256 + tid) * 8;
    f32x4 a = *(const f32x4*)(x + i);
    f32x4 b = *(const f32x4*)(x + i + 4);
    ushort4 lo, hi;
    lo.x = f2bf(a[0]); lo.y = f2bf(a[1]); lo.z = f2bf(a[2]); lo.w = f2bf(a[3]);
    hi.x = f2bf(b[0]); hi.y = f2bf(b[1]); hi.z = f2bf(b[2]); hi.w = f2bf(b[3]);
    *(ushort4*)(xb + i) = lo;
    *(ushort4*)(xb + i + 4) = hi;
  } else {
    // qkvT[s*512+h*64+d][c] = qkv[c][h*128+s*64+d]
    __shared__ float tile[32][33];
    const int idx = id - 2048;
    const int j0 = (idx & 31) * 32;
    const int c0 = (idx >> 5) * 32;
    const int tx = tid & 31, ty = tid >> 5;  // 32 x 8
#pragma unroll
    for (int i = 0; i < 32; i += 8)
      tile[ty + i][tx] = qkv[(size_t)(c0 + ty + i) * 1024 + j0 + tx];
    __syncthreads();
    const int h = j0 >> 7, s = (j0 >> 6) & 1, d0 = j0 & 63;
    const int jp0 = s * 512 + h * 64 + d0;
#pragma unroll
    for (int i = 0; i < 32; i += 8)
      qkvT[(size_t)(jp0 + ty + i) * 512 + c0 + tx] = f2bf(tile[tx][ty + i]);
  }
}

// ---------------- 2) GEMM1 (8 waves, single-buffer, XCD-swizzled): xb @ qkvT^T -> Q, K
// Grid 512 linear. Swizzle: XCD k owns wg [k*64,(k+1)*64) = 8 m-panels x all 8 n-panels,
// so per-XCD working set (2MB A-panels + 1MB B) fits the 4MB XCD L2.
__global__ __launch_bounds__(512) void k_gemm1(
    const unsigned short* __restrict__ A,   // xb [8192][512] bf16
    const unsigned short* __restrict__ Bt,  // qkvT [1024][512] bf16
    unsigned short* __restrict__ Qws,       // [8192][512] col = h*64+d
    unsigned short* __restrict__ Kws) {     // [8192][512]
  __shared__ unsigned short As[128 * 64];
  __shared__ unsigned short Bs[128 * 64];
  const int lin = blockIdx.x;
  const int wg = (lin & 7) * 64 + (lin >> 3);   // bijective: 512 = 8 XCDs x 64
  const int m0 = (wg >> 3) * 128;
  const int n0 = (wg & 7) * 128;
  const int tid = threadIdx.x;
  const int lane = tid & 63;
  const int wave = tid >> 6;       // 8 waves: wm 4 x wn 2
  const int wm = wave >> 1, wn = wave & 1;

  f32x4 acc[2][4] = {};

  const int rlane = lane >> 3;        // row within wave's 8-row stage group
  const int clane = (lane & 7) * 8;   // 8 bf16 = 16B

  for (int kt = 0; kt < 512; kt += 64) {
    __syncthreads();
    // 512 threads x 16B = 64 rows/call; 2 calls for A (128 rows), 2 for B
#pragma unroll
    for (int i = 0; i < 2; ++i) {
      async_cp16(A + (size_t)(m0 + i * 64 + wave * 8 + rlane) * 512 + kt + clane,
                 As + (i * 64 + wave * 8) * 64);
      async_cp16(Bt + (size_t)(n0 + i * 64 + wave * 8 + rlane) * 512 + kt + clane,
                 Bs + (i * 64 + wave * 8) * 64);
    }
    __syncthreads();
#pragma unroll
    for (int kk = 0; kk < 64; kk += 32) {
      s16x8 af[2], bfr[4];
#pragma unroll
      for (int i = 0; i < 2; ++i)
        af[i] = *(const s16x8*)(As + (wm * 32 + i * 16 + (lane & 15)) * 64 + kk + (lane >> 4) * 8);
#pragma unroll
      for (int j = 0; j < 4; ++j)
        bfr[j] = *(const s16x8*)(Bs + (wn * 64 + j * 16 + (lane & 15)) * 64 + kk + (lane >> 4) * 8);
#pragma unroll
      for (int i = 0; i < 2; ++i)
#pragma unroll
        for (int j = 0; j < 4; ++j)
          acc[i][j] = __builtin_amdgcn_mfma_f32_16x16x32_bf16(af[i], bfr[j], acc[i][j], 0, 0, 0);
    }
  }
  const int n_base = n0 + wn * 64;
#pragma unroll
  for (int i = 0; i < 2; ++i) {
    int grow = m0 + wm * 32 + i * 16 + (lane >> 4) * 4;
#pragma unroll
    for (int j = 0; j < 4; ++j) {
      int gcol = n_base + j * 16 + (lane & 15);
      unsigned short* dst;
      float scale;
      if (gcol < 512) { dst = Qws; scale = 0.125f; }        // q, fold SCALE (exact pow2)
      else            { dst = Kws; gcol -= 512; scale = 1.0f; }
#pragma unroll
      for (int r = 0; r < 4; ++r)
        dst[(size_t)(grow + r) * 512 + gcol] = f2bf(acc[i][j][r] * scale);
    }
  }
}

// ---------------- 3) KV partials: KVp[b][h][chunk][dq][l] = sum_{n in chunk} k*v  (f32)
__global__ void k_kv_partial(const unsigned short* __restrict__ Kws,
                             const float* __restrict__ v,   // [2048][512] f32, col h*64+l
                             float* __restrict__ KVp) {
  const int wg = blockIdx.x;      // b*128 + h*16 + chunk
  const int chunk = wg & 15;
  const int h = (wg >> 4) & 7;
  const int b = wg >> 7;
  __shared__ unsigned short Ks[128 * 64];  // 16 KB bf16
  __shared__ float Vs[128 * 64];           // 32 KB f32
  const int tid = threadIdx.x;
  const int lane = tid & 63;
  const int wave = tid >> 6;
  const int n0 = chunk * 128;
  // K staging: 8 lanes/row (16B = 8 bf16), 8 rows/call, 4 calls -> 32 rows/wave
  {
    const int r = wave * 32 + (lane >> 3);
    const int c = (lane & 7) * 8;
#pragma unroll
    for (int i = 0; i < 4; ++i)
      async_cp16(Kws + (size_t)(b * 2048 + n0 + r + i * 8) * 512 + h * 64 + c,
                 Ks + (wave * 32 + i * 8) * 64);
  }
  // V staging (f32): 16 lanes/row (16B = 4 f32), 4 rows/call, 8 calls -> 32 rows/wave
  {
    const int r = wave * 32 + (lane >> 4);
    const int c = (lane & 15) * 4;
#pragma unroll
    for (int i = 0; i < 8; ++i)
      async_cp16(v + (size_t)(n0 + r + i * 4) * 512 + h * 64 + c,
                 Vs + (wave * 32 + i * 4) * 64);
  }
  __syncthreads();
  const int dq0 = (tid & 15) * 4;
  const int l0 = (tid >> 4) * 4;
  float acc[4][4] = {};
#pragma unroll 4
  for (int n = 0; n < 128; ++n) {
    ushort4 ku = *(const ushort4*)(Ks + n * 64 + dq0);
    f32x4 va = *(const f32x4*)(Vs + n * 64 + l0);
    float ka[4] = {bf2f(ku.x), bf2f(ku.y), bf2f(ku.z), bf2f(ku.w)};
#pragma unroll
    for (int a = 0; a < 4; ++a)
#pragma unroll
      for (int c = 0; c < 4; ++c)
        acc[a][c] += ka[a] * va[c];
  }
  float* dst = KVp + (size_t)wg * 4096;
#pragma unroll
  for (int a = 0; a < 4; ++a) {
    f32x4 o;
    o[0] = acc[a][0]; o[1] = acc[a][1]; o[2] = acc[a][2]; o[3] = acc[a][3];
    *(f32x4*)(dst + (dq0 + a) * 64 + l0) = o;
  }
}

// ---------------- 4) reduce + W = KV@proj_h -> WcatT[b][dout][h*64+dq] (bf16)
// 256 blocks (bh x 8 dq-groups): full-chip reduce of the 8.4MB partials (~2-3us vs 10us at 32 blocks)
__global__ void k_w(const float* __restrict__ KVp,
                    const float* __restrict__ proj,   // [512][64] f32
                    unsigned short* __restrict__ WcatT) {  // [B][64][512]
  const int blk = blockIdx.x;   // bh*8 + g
  const int g = blk & 7;        // dq-group: dq = g*8 .. g*8+7
  const int bh = blk >> 3;
  const int h = bh & 7;
  const int b = bh >> 3;
  __shared__ float kv[8 * 64];     // [dq_local][l]
  __shared__ float pj[64 * 64];    // [l][dout]
  const int tid = threadIdx.x;
  {  // reduce 16 chunks for this block's 512-element slice (2 elems/thread)
    const int e = tid * 2;
    const float* src = KVp + (size_t)bh * 16 * 4096 + g * 512 + e;
    float s0 = 0.f, s1 = 0.f;
#pragma unroll
    for (int c = 0; c < 16; ++c) {
      float2 t = *(const float2*)(src + c * 4096);
      s0 += t.x; s1 += t.y;
    }
    kv[e] = s0; kv[e + 1] = s1;
  }
#pragma unroll
  for (int j = 0; j < 16; ++j) {  // stage proj head h: rows h*64..h*64+63 (contiguous 16KB)
    int e = tid + j * 256;
    pj[e] = proj[(size_t)h * 4096 + e];
  }
  __syncthreads();
  const int dout = tid & 63;
  const int dq0 = tid >> 6;    // 0..3; thread also does dq0+4
  float w0 = 0.f, w1 = 0.f;
  for (int l = 0; l < 64; ++l) {
    float p = pj[l * 64 + dout];
    w0 += kv[dq0 * 64 + l] * p;
    w1 += kv[(dq0 + 4) * 64 + l] * p;
  }
  const int dqb = h * 64 + g * 8;
  WcatT[(size_t)(b * 64 + dout) * 512 + dqb + dq0] = f2bf(w0);
  WcatT[(size_t)(b * 64 + dout) * 512 + dqb + dq0 + 4] = f2bf(w1);
}

// ---------------- 5) GEMM2 streaming: out[b] = Qws[b](2048x512) @ WcatT[b]^T(512x64)
// 512 blocks x 1 wave; 16-row m-tile per wave; no LDS, no barriers. All operands L2-hot.
__global__ __launch_bounds__(64) void k_gemm2(
    const unsigned short* __restrict__ Qws,
    const unsigned short* __restrict__ WcatT,
    float* __restrict__ out) {   // [8192][64] f32
  const int m0 = blockIdx.x * 16;
  const int lane = threadIdx.x;
  const unsigned short* Bb = WcatT + (size_t)(m0 >> 11) * 64 * 512;
  const int arow = lane & 15;
  const int koff = (lane >> 4) * 8;
  f32x4 acc[4] = {};
#pragma unroll
  for (int kk = 0; kk < 16; ++kk) {
    s16x8 af = *(const s16x8*)(Qws + (size_t)(m0 + arow) * 512 + kk * 32 + koff);
#pragma unroll
    for (int j = 0; j < 4; ++j) {
      s16x8 bf = *(const s16x8*)(Bb + (size_t)(j * 16 + arow) * 512 + kk * 32 + koff);
      acc[j] = __builtin_amdgcn_mfma_f32_16x16x32_bf16(af, bf, acc[j], 0, 0, 0);
    }
  }
  const int grow = m0 + (lane >> 4) * 4;
#pragma unroll
  for (int j = 0; j < 4; ++j) {
    int gcol = j * 16 + arow;
#pragma unroll
    for (int r = 0; r < 4; ++r)
      out[(size_t)(grow + r) * 64 + gcol] = acc[j][r];
  }
}

extern "C" void kernel_launch(void* const* d_in, const int* in_sizes, int n_in,
                              void* d_out, int out_size, void* d_ws, size_t ws_size,
                              hipStream_t stream) {
  const float* x    = (const float*)d_in[0];  // [4][2048][512] f32
  const float* v    = (const float*)d_in[1];  // [2048][8][64]  f32
  const float* qkv  = (const float*)d_in[2];  // [512][1024]    f32
  const float* proj = (const float*)d_in[3];  // [512][64]      f32
  float* out = (float*)d_out;                 // [4][2048][64]  f32

  char* ws = (char*)d_ws;
  unsigned short* xb   = (unsigned short*)ws; ws += (size_t)8192 * 512 * 2;  // 8.4 MB
  unsigned short* qkvT = (unsigned short*)ws; ws += (size_t)1024 * 512 * 2;  // 1 MB
  unsigned short* Qws  = (unsigned short*)ws; ws += (size_t)8192 * 512 * 2;  // 8.4 MB
  unsigned short* Kws  = (unsigned short*)ws; ws += (size_t)8192 * 512 * 2;  // 8.4 MB
  float*          KVp  = (float*)ws;          ws += (size_t)512 * 4096 * 4;  // 8.4 MB
  unsigned short* Wc   = (unsigned short*)ws; ws += (size_t)4 * 64 * 512 * 2;

  hipLaunchKernelGGL(k_prep, dim3(2560), dim3(256), 0, stream, x, qkv, xb, qkvT);
  hipLaunchKernelGGL(k_gemm1, dim3(512), dim3(512), 0, stream, xb, qkvT, Qws, Kws);
  hipLaunchKernelGGL(k_kv_partial, dim3(512), dim3(256), 0, stream, Kws, v, KVp);
  hipLaunchKernelGGL(k_w, dim3(256), dim3(256), 0, stream, KVp, proj, Wc);
  hipLaunchKernelGGL(k_gemm2, dim3(512), dim3(64), 0, stream, Qws, Wc, out);
}